// Round 23
// baseline (870.631 us; speedup 1.0000x reference)
//
#include <hip/hip_runtime.h>
#include <hip/hip_fp16.h>

#define NN 16384
#define DD 16
#define KK 64
#define QQ 4            // queries per block
#define TPB 256
#define NQW 16          // scan: quads/thread
#define HIST 1024       // buckets width 0.25 over d2 in [0,256)
#define HISTW (HIST/2)
#define LIST_MAX 1024   // -1.8sigma+EPS mass <= ~740 worst (small-norm q) + 5 sigma
#define CAND_MAX 256
#define EPS 1.5f        // f16-approx margin (analytic worst err <= ~0.8)
#define EB 10           // candidate bucket margin >= 1+ceil(2*err/0.25)=8

// XLA:CPU vectorized row-reduce, minor dim 16: lane halving tree. (VALIDATED r5)
__device__ __forceinline__ float halving_sumsq16(const float* v) {
    float p[16];
#pragma unroll
    for (int d = 0; d < 16; ++d) p[d] = __fmul_rn(v[d], v[d]);
    float r8[8];
#pragma unroll
    for (int j = 0; j < 8; ++j) r8[j] = __fadd_rn(p[j], p[j + 8]);
    float r4[4];
#pragma unroll
    for (int j = 0; j < 4; ++j) r4[j] = __fadd_rn(r8[j], r8[j + 4]);
    float r2[2];
#pragma unroll
    for (int j = 0; j < 2; ++j) r2[j] = __fadd_rn(r4[j], r4[j + 2]);
    return __fadd_rn(r2[0], r2[1]);
}

// d2 recipe (VALIDATED r5): f32( f32(sqi+sqj) - 2*dot ), dot = ascending-k fmaf
__device__ __forceinline__ float d2_of(const float* xi, const float* xj,
                                       float sqi, float sqj) {
    float dot = 0.0f;
#pragma unroll
    for (int d = 0; d < DD; ++d) dot = fmaf(xi[d], xj[d], dot);
    return __fsub_rn(__fadd_rn(sqi, sqj), __fmul_rn(2.0f, dot));
}

__device__ __forceinline__ int bucket_of(float d2) {
    int b = (int)__fmul_rn(d2, 4.0f);
    if (b < 0) b = 0;
    if (b >= HIST) b = HIST - 1;
    return b;
}

// listing threshold: -1.8 sigma Gaussian quantile of d2 | sq (chi2 left tail is
// thinner than Gaussian: -1.8sig => ~2-3% mass; r19 calibration: -2.0sig ~ 1%)
__device__ __forceinline__ float tq_of(float s) {
    return 16.0f + s - 1.8f * sqrtf(32.0f + 4.0f * s);
}

#define LOAD_XQ()                                                              \
    float xq[QQ][DD];                                                          \
    float sq[QQ], Tq[QQ];                                                      \
    _Pragma("unroll") for (int q = 0; q < QQ; ++q) {                           \
        const float4* p = reinterpret_cast<const float4*>(x + (iA + q) * DD);  \
        float4 a0 = p[0], a1 = p[1], a2 = p[2], a3 = p[3];                     \
        xq[q][0]=a0.x; xq[q][1]=a0.y; xq[q][2]=a0.z; xq[q][3]=a0.w;            \
        xq[q][4]=a1.x; xq[q][5]=a1.y; xq[q][6]=a1.z; xq[q][7]=a1.w;            \
        xq[q][8]=a2.x; xq[q][9]=a2.y; xq[q][10]=a2.z; xq[q][11]=a2.w;          \
        xq[q][12]=a3.x; xq[q][13]=a3.y; xq[q][14]=a3.z; xq[q][15]=a3.w;        \
        sq[q] = sqf[iA + q];                                                   \
        Tq[q] = tq_of(sq[q]);                                                  \
    }

#define LOAD_XJ(j)                                                             \
    const float4* xj4 = reinterpret_cast<const float4*>(x + (j) * DD);         \
    float4 a0 = xj4[0], a1 = xj4[1], a2 = xj4[2], a3 = xj4[3];                 \
    float xj[DD] = {a0.x, a0.y, a0.z, a0.w, a1.x, a1.y, a1.z, a1.w,            \
                    a2.x, a2.y, a2.z, a2.w, a3.x, a3.y, a3.z, a3.w};

// ---------------- prep: norms + copy x + f16 mirror xh[dpair][j] ----------------
__global__ void prep_kernel(const float* __restrict__ x,
                            float* __restrict__ out_x,
                            float* __restrict__ sqf,
                            __half* __restrict__ xh) {
    int i = blockIdx.x * blockDim.x + threadIdx.x;
    if (i < NN) {
        float v[DD];
#pragma unroll
        for (int d = 0; d < DD; ++d) v[d] = x[i * DD + d];
        sqf[i] = halving_sumsq16(v);
#pragma unroll
        for (int p = 0; p < 8; ++p) {
            xh[((long)p * NN + i) * 2 + 0] = __float2half(v[2 * p]);
            xh[((long)p * NN + i) * 2 + 1] = __float2half(v[2 * p + 1]);
        }
    }
    for (int t = i; t < NN * DD; t += gridDim.x * blockDim.x) {
        out_x[t] = x[t];
    }
}

// ---------------- K1: f16 scan, direct append of (qd2<<16|j) to ws (r20 struct) ----------------
__global__ __launch_bounds__(TPB, 4) void scan_kernel(
        const __half2* __restrict__ xh2,     // [dpair][j]
        const float* __restrict__ sqf,
        unsigned int* __restrict__ ws_cnt,
        unsigned int* __restrict__ ws_list,
        int lm) {                            // runtime list stride/cap
    __shared__ unsigned int s_cnt[QQ];

    const int tid = threadIdx.x;
    const int iA = blockIdx.x * QQ;

    if (tid < QQ) s_cnt[tid] = 0;

    __half2 qh[QQ][8];
    float sqv[QQ], Cq[QQ];
#pragma unroll
    for (int q = 0; q < QQ; ++q) {
#pragma unroll
        for (int p = 0; p < 8; ++p) qh[q][p] = xh2[(long)p * NN + (iA + q)];
        float s = sqf[iA + q];
        sqv[q] = s;
        Cq[q] = 0.5f * (s - tq_of(s) - EPS);   // member iff dot > sj*0.5 + Cq
    }
    __syncthreads();

#pragma unroll 1
    for (int c = 0; c < NQW; ++c) {
        const int qd = c * TPB + tid;               // quad; j = 4*qd + jl
        float4 sjv = reinterpret_cast<const float4*>(sqf)[qd];
        __half2 acc[QQ][4];
#pragma unroll
        for (int q = 0; q < QQ; ++q)
#pragma unroll
            for (int jl = 0; jl < 4; ++jl)
                acc[q][jl] = __half2(__float2half(0.f), __float2half(0.f));
#pragma unroll
        for (int p = 0; p < 8; ++p) {
            const __half2* hp = &xh2[(long)p * NN + 4 * (long)qd];
            __half2 h0 = hp[0], h1 = hp[1], h2 = hp[2], h3 = hp[3];
#pragma unroll
            for (int q = 0; q < QQ; ++q) {
                acc[q][0] = __hfma2(qh[q][p], h0, acc[q][0]);
                acc[q][1] = __hfma2(qh[q][p], h1, acc[q][1]);
                acc[q][2] = __hfma2(qh[q][p], h2, acc[q][2]);
                acc[q][3] = __hfma2(qh[q][p], h3, acc[q][3]);
            }
        }
        float sjq[4] = {sjv.x, sjv.y, sjv.z, sjv.w};
#pragma unroll
        for (int jl = 0; jl < 4; ++jl) {
#pragma unroll
            for (int q = 0; q < QQ; ++q) {
                float dot = __low2float(acc[q][jl]) + __high2float(acc[q][jl]);
                if (dot > fmaf(sjq[jl], 0.5f, Cq[q])) {
                    float d2a = (sqv[q] + sjq[jl]) - 2.0f * dot;
                    int qd2 = (int)__fmul_rn(d2a, 256.0f);
                    qd2 = qd2 < 0 ? 0 : (qd2 > 65535 ? 65535 : qd2);
                    unsigned int pos = atomicAdd(&s_cnt[q], 1u);
                    if (pos < (unsigned int)lm)
                        ws_list[(long)(iA + q) * lm + pos] =
                            ((unsigned int)qd2 << 16) |
                            (unsigned int)(4 * qd + jl);
                }
            }
        }
    }
    __syncthreads();
    if (tid < QQ) ws_cnt[iA + tid] = s_cnt[tid];
}

// ---------------- K2: approx-key select + single small exact gather (r20 struct) ----------------
__global__ __launch_bounds__(TPB) void select_kernel(
        const float* __restrict__ x,
        const int* __restrict__ pid,
        const float* __restrict__ sqf,
        const unsigned int* __restrict__ ws_cnt,
        const unsigned int* __restrict__ ws_list,
        float* __restrict__ out_src,
        float* __restrict__ out_dst,
        float* __restrict__ out_y,
        float* __restrict__ out_ef,
        float* __restrict__ out_mask,
        int lm) {
    __shared__ unsigned int list32[QQ][LIST_MAX];   // 16 KB (qd2<<16|j)
    __shared__ unsigned int hist[QQ][HISTW];        // 8 KB packed u16 pairs
    __shared__ unsigned int cand_key[QQ][CAND_MAX]; // 4 KB
    __shared__ int cand_idx[QQ][CAND_MAX];          // 4 KB
    __shared__ unsigned int wavesum[QQ][TPB / 64];
    __shared__ int s_bsel[QQ];
    __shared__ unsigned int s_lowcnt[QQ], s_candcnt[QQ], s_lc[QQ];
    __shared__ int s_fb[QQ];

    const int bid = blockIdx.x;
    const int tid = threadIdx.x;
    const int lane = tid & 63;
    const int w = tid >> 6;
    const int iA = bid * QQ;

    for (int t = tid; t < QQ * HISTW; t += TPB)
        ((unsigned int*)hist)[t] = 0;
    if (tid < QQ) {
        s_lowcnt[tid] = 0; s_candcnt[tid] = 0; s_bsel[tid] = -1;
        unsigned int c = ws_cnt[iA + tid];
        s_lc[tid] = c < (unsigned int)lm ? c : (unsigned int)lm;
        if (s_lc[tid] > LIST_MAX) s_lc[tid] = LIST_MAX;
    }
    LOAD_XQ();
    __syncthreads();

    // stage lists (coalesced) + approx hist + lowcnt (no gathers)
    for (int q = 0; q < QQ; ++q) {
        const unsigned int* src = ws_list + (long)(iA + q) * lm;
        const int lc = (int)s_lc[q];
        const int lthr = (int)__fmul_rn(Tq[q] - EPS, 256.0f) - 2;
        unsigned int my = 0;
        for (int e = tid; e < lc; e += TPB) {
            unsigned int ent = src[e];
            list32[q][e] = ent;
            int b = (int)(ent >> 22);               // qd2>>6 bucket
            atomicAdd(&hist[q][b >> 1], 1u << ((b & 1) << 4));
            my += ((int)(ent >> 16) < lthr) ? 1u : 0u;
        }
        unsigned int v = my;
#pragma unroll
        for (int off = 1; off < 64; off <<= 1) v += __shfl_xor(v, off, 64);
        if (lane == 0 && v) atomicAdd(&s_lowcnt[q], v);
    }
    __syncthreads();

    // F#1: prefix over approx hist -> bucket of (K+1)-th approx key (VALIDATED)
    {
        unsigned int local[QQ], inc[QQ];
        unsigned int pc0[QQ], pc1[QQ], pc2[QQ], pc3[QQ];
#pragma unroll
        for (int q = 0; q < QQ; ++q) {
            unsigned int h0 = hist[q][2 * tid];
            unsigned int h1 = hist[q][2 * tid + 1];
            pc0[q] = h0 & 0xFFFFu; pc1[q] = h0 >> 16;
            pc2[q] = h1 & 0xFFFFu; pc3[q] = h1 >> 16;
            unsigned int s = pc0[q] + pc1[q] + pc2[q] + pc3[q];
            local[q] = s;
            unsigned int v = s;
#pragma unroll
            for (int off = 1; off < 64; off <<= 1) {
                unsigned int n = __shfl_up(v, off, 64);
                if (lane >= off) v += n;
            }
            inc[q] = v;
        }
        if (lane == 63)
#pragma unroll
            for (int q = 0; q < QQ; ++q) wavesum[q][w] = inc[q];
        __syncthreads();
#pragma unroll
        for (int q = 0; q < QQ; ++q) {
            unsigned int woff = 0;
            for (int ww = 0; ww < w; ++ww) woff += wavesum[q][ww];
            unsigned int cum = inc[q] + woff;
            unsigned int prev = cum - local[q];
            if (prev < KK + 1 && KK + 1 <= cum) {
                unsigned int acc = prev;
                int b = 4 * tid;
                if (acc + pc0[q] < KK + 1) { acc += pc0[q]; ++b;
                    if (acc + pc1[q] < KK + 1) { acc += pc1[q]; ++b;
                        if (acc + pc2[q] < KK + 1) { acc += pc2[q]; ++b; } } }
                s_bsel[q] = b;
            }
        }
    }
    __syncthreads();

    // guards -> flags; candidates: bucket <= b65+EB, single exact gather
    if (tid < QQ) {
        const int b65 = s_bsel[tid];
        const float cutq = Tq[tid] + EPS;
        const int qcutb = ((int)__fmul_rn(fminf(cutq, 250.0f), 256.0f)) >> 6;
        s_fb[tid] = (ws_cnt[iA + tid] > (unsigned int)lm) ||
                    (s_lc[tid] > LIST_MAX) ||
                    (s_lowcnt[tid] < KK + 1) || (b65 < 0) ||
                    (b65 + EB + 2 > qcutb);         // window must lie in listed range
    }
    __syncthreads();

#pragma unroll
    for (int q = 0; q < QQ; ++q) {
        if (s_fb[q]) continue;
        const int cutb = s_bsel[q] + EB;
        const int lc = (int)s_lc[q];
        for (int e = tid; e < lc; e += TPB) {
            const unsigned int ent = list32[q][e];
            if ((int)(ent >> 22) <= cutb) {
                const int j = (int)(ent & 0xFFFFu);
                if (j == iA + q) continue;
                unsigned int pos = atomicAdd(&s_candcnt[q], 1u);
                if (pos < CAND_MAX) {
                    LOAD_XJ(j);
                    float d2 = d2_of(xq[q], xj, sq[q], sqf[j]);
                    unsigned int u = __float_as_uint(d2);
                    u ^= (u & 0x80000000u) ? 0xFFFFFFFFu : 0x80000000u;
                    cand_key[q][pos] = u;
                    cand_idx[q][pos] = j;
                }
            }
        }
    }
    __syncthreads();
    if (tid < QQ && s_candcnt[tid] > CAND_MAX) s_fb[tid] = 1;
    __syncthreads();
    const int anyfb = s_fb[0] | s_fb[1] | s_fb[2] | s_fb[3];

    // ---- fallback: validated exact full pipeline (r20-execution-tested) ----
    if (anyfb) {
        if (tid < QQ && s_fb[tid]) { s_candcnt[tid] = 0; s_bsel[tid] = HIST - 1; }
#pragma unroll
        for (int q = 0; q < QQ; ++q)
            if (s_fb[q])
                for (int t = tid; t < HISTW; t += TPB) hist[q][t] = 0;
        __syncthreads();
        for (int j = tid; j < NN; j += TPB) {
            LOAD_XJ(j);
            const float sj = sqf[j];
#pragma unroll
            for (int q = 0; q < QQ; ++q) {
                if (s_fb[q] && j != iA + q) {
                    float d2 = d2_of(xq[q], xj, sq[q], sj);
                    int b = bucket_of(d2);
                    atomicAdd(&hist[q][b >> 1], 1u << ((b & 1) << 4));
                }
            }
        }
        __syncthreads();
        {
            unsigned int local[QQ], inc[QQ];
            unsigned int pc0[QQ], pc1[QQ], pc2[QQ], pc3[QQ];
#pragma unroll
            for (int q = 0; q < QQ; ++q) {
                unsigned int h0 = hist[q][2 * tid];
                unsigned int h1 = hist[q][2 * tid + 1];
                pc0[q] = h0 & 0xFFFFu; pc1[q] = h0 >> 16;
                pc2[q] = h1 & 0xFFFFu; pc3[q] = h1 >> 16;
                unsigned int s = pc0[q] + pc1[q] + pc2[q] + pc3[q];
                local[q] = s;
                unsigned int v = s;
#pragma unroll
                for (int off = 1; off < 64; off <<= 1) {
                    unsigned int n = __shfl_up(v, off, 64);
                    if (lane >= off) v += n;
                }
                inc[q] = v;
            }
            if (lane == 63)
#pragma unroll
                for (int q = 0; q < QQ; ++q) wavesum[q][w] = inc[q];
            __syncthreads();
#pragma unroll
            for (int q = 0; q < QQ; ++q) {
                if (!s_fb[q]) continue;
                unsigned int woff = 0;
                for (int ww = 0; ww < w; ++ww) woff += wavesum[q][ww];
                unsigned int cum = inc[q] + woff;
                unsigned int prev = cum - local[q];
                if (prev < KK && KK <= cum) {
                    unsigned int acc = prev;
                    int b = 4 * tid;
                    if (acc + pc0[q] < KK) { acc += pc0[q]; ++b;
                        if (acc + pc1[q] < KK) { acc += pc1[q]; ++b;
                            if (acc + pc2[q] < KK) { acc += pc2[q]; ++b; } } }
                    s_bsel[q] = b;
                }
            }
        }
        __syncthreads();
        for (int j = tid; j < NN; j += TPB) {
            LOAD_XJ(j);
            const float sj = sqf[j];
#pragma unroll
            for (int q = 0; q < QQ; ++q) {
                if (s_fb[q] && j != iA + q) {
                    float d2 = d2_of(xq[q], xj, sq[q], sj);
                    if (bucket_of(d2) <= s_bsel[q]) {
                        unsigned int pos = atomicAdd(&s_candcnt[q], 1u);
                        if (pos < CAND_MAX) {
                            unsigned int u = __float_as_uint(d2);
                            u ^= (u & 0x80000000u) ? 0xFFFFFFFFu : 0x80000000u;
                            cand_key[q][pos] = u;
                            cand_idx[q][pos] = j;
                        }
                    }
                }
            }
        }
    }
    __syncthreads();

    // H: rank by (key asc, index asc) + write outputs (VALIDATED)
    for (int q = 0; q < QQ; ++q) {
        const int iq = iA + q;
        const int mypid = pid[iq];
        int c = (int)s_candcnt[q];
        if (c > CAND_MAX) c = CAND_MAX;
        for (int t = tid; t < c; t += TPB) {
            const unsigned int kt = cand_key[q][t];
            const int jt = cand_idx[q][t];
            int rank = 0;
            for (int u = 0; u < c; ++u) {
                unsigned int ku = cand_key[q][u];
                rank += (ku < kt) || (ku == kt && cand_idx[q][u] < jt);
            }
            if (rank < KK) {
                const long e = (long)iq * KK + rank;
                out_src[e] = (float)jt;

                const float* xjp = x + jt * DD;
                float diff[DD], sum[DD];
#pragma unroll
                for (int d = 0; d < DD; ++d) {
                    float a = xjp[d], b = xq[q][d];
                    diff[d] = __fsub_rn(a, b);   // x_src - x_dst
                    sum[d]  = __fadd_rn(a, b);   // x_src + x_dst
                }
                const float s2 = halving_sumsq16(diff);    // VALIDATED tree
                const bool m = __fsqrt_rn(s2) < 6.0f;
                out_mask[e] = m ? 1.0f : 0.0f;
                const int pj = pid[jt];
                out_y[e] = (m && pj == mypid && pj > 0) ? 1.0f : 0.0f;

                float* ef = out_ef + e * (2 * DD);
#pragma unroll
                for (int d = 0; d < DD; ++d) ef[d] = m ? diff[d] : 0.0f;
#pragma unroll
                for (int d = 0; d < DD; ++d) ef[DD + d] = m ? sum[d] : 0.0f;
            }
        }
    }

    // dst column of edge_index
    for (int t = tid; t < QQ * KK; t += TPB) {
        out_dst[(long)iA * KK + t] = (float)(iA + t / KK);
    }
}

extern "C" void kernel_launch(void* const* d_in, const int* in_sizes, int n_in,
                              void* d_out, int out_size, void* d_ws, size_t ws_size,
                              hipStream_t stream) {
    const float* x = (const float*)d_in[0];
    const int* pid = (const int*)d_in[1];
    float* out = (float*)d_out;

    float* out_x   = out;                                // N*D
    float* out_src = out_x + NN * DD;                    // N*K
    float* out_dst = out_src + NN * KK;                  // N*K
    float* out_y   = out_dst + NN * KK;                  // N*K
    float* out_ef  = out_y + NN * KK;                    // N*K*2D
    float* out_mask = out_ef + (long)NN * KK * 2 * DD;   // N*K

    // ws: sqf f32[NN] | xh half[NN*16] | cnt u32[NN] | lists u32[NN][lm]
    char* wsb = (char*)d_ws;
    float* sqf = (float*)wsb;
    __half* xh = (__half*)(wsb + (long)NN * 4);
    unsigned int* ws_cnt =
        (unsigned int*)(wsb + (long)NN * 4 + (long)NN * DD * 2);
    unsigned int* ws_list =
        (unsigned int*)(wsb + (long)NN * 4 + (long)NN * DD * 2 + (long)NN * 4);

    // runtime clamp: never exceed the provided workspace (small ws -> fallback)
    size_t fixed = (long)NN * 4 + (long)NN * DD * 2 + (long)NN * 4;
    long avail = ws_size > fixed ? (long)((ws_size - fixed) / ((long)NN * 4)) : 0;
    int lm = (int)(avail < LIST_MAX ? avail : LIST_MAX);
    if (lm < 1) lm = 1;

    prep_kernel<<<NN / 256, 256, 0, stream>>>(x, out_x, sqf, xh);
    scan_kernel<<<NN / QQ, TPB, 0, stream>>>((const __half2*)xh, sqf,
                                             ws_cnt, ws_list, lm);
    select_kernel<<<NN / QQ, TPB, 0, stream>>>(x, pid, sqf, ws_cnt, ws_list,
                                               out_src, out_dst, out_y,
                                               out_ef, out_mask, lm);
}

// Round 24
// 390.570 us; speedup vs baseline: 2.2291x; 2.2291x over previous
//
#include <hip/hip_runtime.h>
#include <hip/hip_fp16.h>

#define NN 16384
#define DD 16
#define KK 64
#define QQ 4            // queries per block
#define TPB 256
#define NQW 16          // scan: quads/thread
#define HIST 1024       // buckets width 0.25 over d2 in [0,256)
#define HISTW (HIST/2)
#define LIST_MAX 1024   // membership -1.8sigma+EPS: worst-case list ~770
#define CAND_MAX 256
#define EPS 1.5f        // f16-approx margin (r19: held for all exercised queries)

// XLA:CPU vectorized row-reduce, minor dim 16: lane halving tree. (VALIDATED r5)
__device__ __forceinline__ float halving_sumsq16(const float* v) {
    float p[16];
#pragma unroll
    for (int d = 0; d < 16; ++d) p[d] = __fmul_rn(v[d], v[d]);
    float r8[8];
#pragma unroll
    for (int j = 0; j < 8; ++j) r8[j] = __fadd_rn(p[j], p[j + 8]);
    float r4[4];
#pragma unroll
    for (int j = 0; j < 4; ++j) r4[j] = __fadd_rn(r8[j], r8[j + 4]);
    float r2[2];
#pragma unroll
    for (int j = 0; j < 2; ++j) r2[j] = __fadd_rn(r4[j], r4[j + 2]);
    return __fadd_rn(r2[0], r2[1]);
}

// d2 recipe (VALIDATED r5): f32( f32(sqi+sqj) - 2*dot ), dot = ascending-k fmaf
__device__ __forceinline__ float d2_of(const float* xi, const float* xj,
                                       float sqi, float sqj) {
    float dot = 0.0f;
#pragma unroll
    for (int d = 0; d < DD; ++d) dot = fmaf(xi[d], xj[d], dot);
    return __fsub_rn(__fadd_rn(sqi, sqj), __fmul_rn(2.0f, dot));
}

__device__ __forceinline__ int bucket_of(float d2) {
    int b = (int)__fmul_rn(d2, 4.0f);
    if (b < 0) b = 0;
    if (b >= HIST) b = HIST - 1;
    return b;
}

// listing threshold at -1.8 sigma: EMPIRICAL ANCHOR — r13..r16 ran exact lists
// at this cut with guard {count >= K+1} and never fell back (all 16384 queries).
__device__ __forceinline__ float tq_of(float s) {
    return 16.0f + s - 1.8f * sqrtf(32.0f + 4.0f * s);
}

#define LOAD_XQ()                                                              \
    float xq[QQ][DD];                                                          \
    float sq[QQ], Tq[QQ];                                                      \
    _Pragma("unroll") for (int q = 0; q < QQ; ++q) {                           \
        const float4* p = reinterpret_cast<const float4*>(x + (iA + q) * DD);  \
        float4 a0 = p[0], a1 = p[1], a2 = p[2], a3 = p[3];                     \
        xq[q][0]=a0.x; xq[q][1]=a0.y; xq[q][2]=a0.z; xq[q][3]=a0.w;            \
        xq[q][4]=a1.x; xq[q][5]=a1.y; xq[q][6]=a1.z; xq[q][7]=a1.w;            \
        xq[q][8]=a2.x; xq[q][9]=a2.y; xq[q][10]=a2.z; xq[q][11]=a2.w;          \
        xq[q][12]=a3.x; xq[q][13]=a3.y; xq[q][14]=a3.z; xq[q][15]=a3.w;        \
        sq[q] = sqf[iA + q];                                                   \
        Tq[q] = tq_of(sq[q]);                                                  \
    }

#define LOAD_XJ(j)                                                             \
    const float4* xj4 = reinterpret_cast<const float4*>(x + (j) * DD);         \
    float4 a0 = xj4[0], a1 = xj4[1], a2 = xj4[2], a3 = xj4[3];                 \
    float xj[DD] = {a0.x, a0.y, a0.z, a0.w, a1.x, a1.y, a1.z, a1.w,            \
                    a2.x, a2.y, a2.z, a2.w, a3.x, a3.y, a3.z, a3.w};

// ---------------- prep: norms + copy x + f16 mirror xh[dpair][j] ----------------
__global__ void prep_kernel(const float* __restrict__ x,
                            float* __restrict__ out_x,
                            float* __restrict__ sqf,
                            __half* __restrict__ xh) {
    int i = blockIdx.x * blockDim.x + threadIdx.x;
    if (i < NN) {
        float v[DD];
#pragma unroll
        for (int d = 0; d < DD; ++d) v[d] = x[i * DD + d];
        sqf[i] = halving_sumsq16(v);
#pragma unroll
        for (int p = 0; p < 8; ++p) {
            xh[((long)p * NN + i) * 2 + 0] = __float2half(v[2 * p]);
            xh[((long)p * NN + i) * 2 + 1] = __float2half(v[2 * p + 1]);
        }
    }
    for (int t = i; t < NN * DD; t += gridDim.x * blockDim.x) {
        out_x[t] = x[t];
    }
}

// ---------------- K1: packed-f16 margined scan + one-time harvest (VALIDATED r19) ----------------
// Membership: approx_d2 < Tq + EPS  ⊇  {exact d2 < Tq}. Select's exact-side
// guard (excnt >= KK+1) certifies coverage per query; else full-rescan fallback.
__global__ __launch_bounds__(TPB, 4) void scan_kernel(
        const __half2* __restrict__ xh2,     // [dpair][j] half2
        const float* __restrict__ sqf,
        unsigned int* __restrict__ ws_cnt,
        unsigned short* __restrict__ ws_list) {
    __shared__ unsigned short bm[NQW][TPB];         // 8 KB want-bits (u16/quad)
    __shared__ unsigned short list[QQ][LIST_MAX];   // 8 KB
    __shared__ unsigned int wcnt[TPB / 64][QQ];
    __shared__ unsigned int s_listcnt[QQ];

    const int tid = threadIdx.x;
    const int lane = tid & 63;
    const int w = tid >> 6;
    const int iA = blockIdx.x * QQ;

    __half2 qh[QQ][8];
    float Cq[QQ];
#pragma unroll
    for (int q = 0; q < QQ; ++q)
#pragma unroll
        for (int p = 0; p < 8; ++p)
            qh[q][p] = xh2[(long)p * NN + (iA + q)];
#pragma unroll
    for (int q = 0; q < QQ; ++q) {
        float s = sqf[iA + q];
        // member iff dot > (sq + sj - Tq - EPS)/2 = sj*0.5 + Cq
        Cq[q] = 0.5f * (s - tq_of(s) - EPS);
    }

    // hot loop: quad of 4 consecutive j; 8 coalesced 16B loads + 128 pk_fma
#pragma unroll 1
    for (int c = 0; c < NQW; ++c) {
        const int qd = c * TPB + tid;               // quad index; j = 4*qd + jl
        float4 sjv = reinterpret_cast<const float4*>(sqf)[qd];
        __half2 acc[QQ][4];
#pragma unroll
        for (int q = 0; q < QQ; ++q)
#pragma unroll
            for (int jl = 0; jl < 4; ++jl)
                acc[q][jl] = __half2(__float2half(0.f), __float2half(0.f));
#pragma unroll
        for (int p = 0; p < 8; ++p) {
            const __half2* hp = &xh2[(long)p * NN + 4 * (long)qd];
            __half2 h0 = hp[0], h1 = hp[1], h2 = hp[2], h3 = hp[3];
#pragma unroll
            for (int q = 0; q < QQ; ++q) {
                acc[q][0] = __hfma2(qh[q][p], h0, acc[q][0]);
                acc[q][1] = __hfma2(qh[q][p], h1, acc[q][1]);
                acc[q][2] = __hfma2(qh[q][p], h2, acc[q][2]);
                acc[q][3] = __hfma2(qh[q][p], h3, acc[q][3]);
            }
        }
        unsigned int bits = 0;
        float sjq[4] = {sjv.x, sjv.y, sjv.z, sjv.w};
#pragma unroll
        for (int jl = 0; jl < 4; ++jl) {
#pragma unroll
            for (int q = 0; q < QQ; ++q) {
                float dot = __low2float(acc[q][jl]) + __high2float(acc[q][jl]);
                float thr = fmaf(sjq[jl], 0.5f, Cq[q]);
                if (dot > thr) bits |= (1u << (jl * 4 + q));
            }
        }
        bm[c][tid] = (unsigned short)bits;
    }
    __syncthreads();

    // one-time harvest (VALIDATED r15/r16/r19): popc -> wave prefix -> scatter
    {
        unsigned int cnt[QQ] = {0, 0, 0, 0};
#pragma unroll 1
        for (int c = 0; c < NQW; ++c) {
            unsigned int w16 = bm[c][tid];
#pragma unroll
            for (int q = 0; q < QQ; ++q)
                cnt[q] += (unsigned int)__popc(w16 & (0x1111u << q));
        }
        unsigned int excl[QQ];
#pragma unroll
        for (int q = 0; q < QQ; ++q) {
            unsigned int v = cnt[q];
#pragma unroll
            for (int off = 1; off < 64; off <<= 1) {
                unsigned int n = __shfl_up(v, off, 64);
                if (lane >= off) v += n;
            }
            excl[q] = v - cnt[q];
            if (lane == 63) wcnt[w][q] = v;
        }
        __syncthreads();
        if (tid < QQ)
            s_listcnt[tid] = wcnt[0][tid] + wcnt[1][tid] + wcnt[2][tid] + wcnt[3][tid];
        unsigned int cur[QQ];
#pragma unroll
        for (int q = 0; q < QQ; ++q) {
            unsigned int b = 0;
            for (int ww = 0; ww < w; ++ww) b += wcnt[ww][q];
            cur[q] = b + excl[q];
        }
#pragma unroll 1
        for (int c = 0; c < NQW; ++c) {
            unsigned int t16 = bm[c][tid];
            while (t16) {
                int b = __ffs(t16) - 1;
                int q = b & 3;
                int jl = b >> 2;
                unsigned int pos = cur[q]++;
                if (pos < LIST_MAX)
                    list[q][pos] = (unsigned short)((c * TPB + tid) * 4 + jl);
                t16 &= t16 - 1;
            }
        }
    }
    __syncthreads();

    // dump lists + raw counts to ws
    for (int q = 0; q < QQ; ++q) {
        int lc = (int)min(s_listcnt[q], (unsigned int)LIST_MAX);
        unsigned short* dst = ws_list + ((long)iA + q) * LIST_MAX;
        for (int e = tid; e < lc; e += TPB) dst[e] = list[q][e];
    }
    if (tid < QQ) ws_cnt[iA + tid] = s_listcnt[tid];
}

// ---------------- K2: select + rank + write (VALIDATED r13/r16 structure) ----------------
__global__ __launch_bounds__(TPB) void select_kernel(
        const float* __restrict__ x,
        const int* __restrict__ pid,
        const float* __restrict__ sqf,
        const unsigned int* __restrict__ ws_cnt,
        const unsigned short* __restrict__ ws_list,
        float* __restrict__ out_src,
        float* __restrict__ out_dst,
        float* __restrict__ out_y,
        float* __restrict__ out_ef,
        float* __restrict__ out_mask) {
    __shared__ unsigned short list[QQ][LIST_MAX];   // 8 KB
    __shared__ unsigned int hist[QQ][HISTW];        // 8 KB
    __shared__ unsigned int cand_key[QQ][CAND_MAX]; // 4 KB
    __shared__ int cand_idx[QQ][CAND_MAX];          // 4 KB
    __shared__ unsigned int wavesum[QQ][TPB / 64];
    __shared__ int s_bsel[QQ];
    __shared__ unsigned int s_excnt[QQ], s_candcnt[QQ], s_lc[QQ];
    __shared__ int s_fb[QQ];

    const int bid = blockIdx.x;
    const int tid = threadIdx.x;
    const int lane = tid & 63;
    const int w = tid >> 6;
    const int iA = bid * QQ;

    for (int t = tid; t < QQ * HISTW; t += TPB)
        ((unsigned int*)hist)[t] = 0;
    if (tid < QQ) {
        s_excnt[tid] = 0; s_candcnt[tid] = 0; s_bsel[tid] = HIST - 1;
        s_lc[tid] = min(ws_cnt[iA + tid], (unsigned int)LIST_MAX);
    }
    LOAD_XQ();
    __syncthreads();

    for (int q = 0; q < QQ; ++q) {
        const unsigned short* src = ws_list + ((long)iA + q) * LIST_MAX;
        const int lc = (int)s_lc[q];
        for (int e = tid; e < lc; e += TPB) list[q][e] = src[e];
    }
    __syncthreads();

    // E0 (VALIDATED r13..r19): exact d2 per entry -> hist + excnt guard.
    // excnt = #{exact < Tq} >= KK+1 (incl self) certifies 64th exact key < Tq;
    // scan's EPS margin then gives {exact<Tq} ⊆ list -> top-64 ⊆ list.
    // At -1.8sigma this condition held for ALL queries in r13..r16 (measured).
    for (int q = 0; q < QQ; ++q) {
        const int lc = (int)s_lc[q];
        unsigned int my = 0;
        for (int e = tid; e < lc; e += TPB) {
            const int j = list[q][e];
            LOAD_XJ(j);
            float d2 = d2_of(xq[q], xj, sq[q], sqf[j]);
            my += (d2 < Tq[q]) ? 1u : 0u;
            int b = bucket_of(d2);
            atomicAdd(&hist[q][b >> 1], 1u << ((b & 1) << 4));
        }
        unsigned int v = my;
#pragma unroll
        for (int off = 1; off < 64; off <<= 1) v += __shfl_xor(v, off, 64);
        if (lane == 0 && v) atomicAdd(&s_excnt[q], v);
    }
    __syncthreads();

    if (tid < QQ)
        s_fb[tid] = (ws_cnt[iA + tid] > LIST_MAX) || (s_excnt[tid] < KK + 1);
    __syncthreads();
    const int anyfb = s_fb[0] | s_fb[1] | s_fb[2] | s_fb[3];

    if (anyfb) {
#pragma unroll
        for (int q = 0; q < QQ; ++q)
            if (s_fb[q])
                for (int t = tid; t < HISTW; t += TPB) hist[q][t] = 0;
        __syncthreads();
        for (int j = tid; j < NN; j += TPB) {
            LOAD_XJ(j);
            const float sj = sqf[j];
#pragma unroll
            for (int q = 0; q < QQ; ++q) {
                if (s_fb[q] && j != iA + q) {
                    float d2 = d2_of(xq[q], xj, sq[q], sj);
                    int b = bucket_of(d2);
                    atomicAdd(&hist[q][b >> 1], 1u << ((b & 1) << 4));
                }
            }
        }
    }
    __syncthreads();

    // F: prefix-scan over packed buckets -> bucket of need-th key (VALIDATED)
    {
        unsigned int local[QQ], inc[QQ];
        unsigned int pc0[QQ], pc1[QQ], pc2[QQ], pc3[QQ];
#pragma unroll
        for (int q = 0; q < QQ; ++q) {
            unsigned int h0 = hist[q][2 * tid];
            unsigned int h1 = hist[q][2 * tid + 1];
            pc0[q] = h0 & 0xFFFFu; pc1[q] = h0 >> 16;
            pc2[q] = h1 & 0xFFFFu; pc3[q] = h1 >> 16;
            unsigned int s = pc0[q] + pc1[q] + pc2[q] + pc3[q];
            local[q] = s;
            unsigned int v = s;
#pragma unroll
            for (int off = 1; off < 64; off <<= 1) {
                unsigned int n = __shfl_up(v, off, 64);
                if (lane >= off) v += n;
            }
            inc[q] = v;
        }
        if (lane == 63)
#pragma unroll
            for (int q = 0; q < QQ; ++q) wavesum[q][w] = inc[q];
        __syncthreads();
#pragma unroll
        for (int q = 0; q < QQ; ++q) {
            const unsigned int need = s_fb[q] ? KK : (KK + 1);
            unsigned int woff = 0;
            for (int ww = 0; ww < w; ++ww) woff += wavesum[q][ww];
            unsigned int cum = inc[q] + woff;
            unsigned int prev = cum - local[q];
            if (prev < need && need <= cum) {
                unsigned int acc = prev;
                int b = 4 * tid;
                if (acc + pc0[q] < need) { acc += pc0[q]; ++b;
                    if (acc + pc1[q] < need) { acc += pc1[q]; ++b;
                        if (acc + pc2[q] < need) { acc += pc2[q]; ++b; } } }
                s_bsel[q] = b;
            }
        }
    }
    __syncthreads();

    // G: candidate gather (self excluded)
#pragma unroll
    for (int q = 0; q < QQ; ++q) {
        if (!s_fb[q]) {
            const int bsel = s_bsel[q];
            const int lc = (int)s_lc[q];
            for (int e = tid; e < lc; e += TPB) {
                const int j = list[q][e];
                LOAD_XJ(j);
                float d2 = d2_of(xq[q], xj, sq[q], sqf[j]);
                if (bucket_of(d2) <= bsel && j != iA + q) {
                    unsigned int pos = atomicAdd(&s_candcnt[q], 1u);
                    if (pos < CAND_MAX) {
                        unsigned int u = __float_as_uint(d2);
                        u ^= (u & 0x80000000u) ? 0xFFFFFFFFu : 0x80000000u;
                        cand_key[q][pos] = u;
                        cand_idx[q][pos] = j;
                    }
                }
            }
        }
    }
    if (anyfb) {
        for (int j = tid; j < NN; j += TPB) {
            LOAD_XJ(j);
            const float sj = sqf[j];
#pragma unroll
            for (int q = 0; q < QQ; ++q) {
                if (s_fb[q] && j != iA + q) {
                    float d2 = d2_of(xq[q], xj, sq[q], sj);
                    if (bucket_of(d2) <= s_bsel[q]) {
                        unsigned int pos = atomicAdd(&s_candcnt[q], 1u);
                        if (pos < CAND_MAX) {
                            unsigned int u = __float_as_uint(d2);
                            u ^= (u & 0x80000000u) ? 0xFFFFFFFFu : 0x80000000u;
                            cand_key[q][pos] = u;
                            cand_idx[q][pos] = j;
                        }
                    }
                }
            }
        }
    }
    __syncthreads();

    // H: rank by (key asc, index asc) + write outputs (VALIDATED)
    for (int q = 0; q < QQ; ++q) {
        const int iq = iA + q;
        const int mypid = pid[iq];
        int c = (int)s_candcnt[q];
        if (c > CAND_MAX) c = CAND_MAX;
        for (int t = tid; t < c; t += TPB) {
            const unsigned int kt = cand_key[q][t];
            const int jt = cand_idx[q][t];
            int rank = 0;
            for (int u = 0; u < c; ++u) {
                unsigned int ku = cand_key[q][u];
                rank += (ku < kt) || (ku == kt && cand_idx[q][u] < jt);
            }
            if (rank < KK) {
                const long e = (long)iq * KK + rank;
                out_src[e] = (float)jt;

                const float* xjp = x + jt * DD;
                float diff[DD], sum[DD];
#pragma unroll
                for (int d = 0; d < DD; ++d) {
                    float a = xjp[d], b = xq[q][d];
                    diff[d] = __fsub_rn(a, b);   // x_src - x_dst
                    sum[d]  = __fadd_rn(a, b);   // x_src + x_dst
                }
                const float s2 = halving_sumsq16(diff);    // VALIDATED tree
                const bool m = __fsqrt_rn(s2) < 6.0f;
                out_mask[e] = m ? 1.0f : 0.0f;
                const int pj = pid[jt];
                out_y[e] = (m && pj == mypid && pj > 0) ? 1.0f : 0.0f;

                float* ef = out_ef + e * (2 * DD);
#pragma unroll
                for (int d = 0; d < DD; ++d) ef[d] = m ? diff[d] : 0.0f;
#pragma unroll
                for (int d = 0; d < DD; ++d) ef[DD + d] = m ? sum[d] : 0.0f;
            }
        }
    }

    // dst column of edge_index
    for (int t = tid; t < QQ * KK; t += TPB) {
        out_dst[(long)iA * KK + t] = (float)(iA + t / KK);
    }
}

extern "C" void kernel_launch(void* const* d_in, const int* in_sizes, int n_in,
                              void* d_out, int out_size, void* d_ws, size_t ws_size,
                              hipStream_t stream) {
    const float* x = (const float*)d_in[0];
    const int* pid = (const int*)d_in[1];
    float* out = (float*)d_out;

    float* out_x   = out;                                // N*D
    float* out_src = out_x + NN * DD;                    // N*K
    float* out_dst = out_src + NN * KK;                  // N*K
    float* out_y   = out_dst + NN * KK;                  // N*K
    float* out_ef  = out_y + NN * KK;                    // N*K*2D
    float* out_mask = out_ef + (long)NN * KK * 2 * DD;   // N*K

    // ws: sqf f32[NN] | xh half[NN*16] | cnt u32[NN] | lists u16[NN][1024] (~34 MB)
    char* wsb = (char*)d_ws;
    float* sqf = (float*)wsb;
    __half* xh = (__half*)(wsb + (long)NN * 4);
    unsigned int* ws_cnt =
        (unsigned int*)(wsb + (long)NN * 4 + (long)NN * DD * 2);
    unsigned short* ws_list =
        (unsigned short*)(wsb + (long)NN * 4 + (long)NN * DD * 2 + (long)NN * 4);

    prep_kernel<<<NN / 256, 256, 0, stream>>>(x, out_x, sqf, xh);
    scan_kernel<<<NN / QQ, TPB, 0, stream>>>((const __half2*)xh, sqf,
                                             ws_cnt, ws_list);
    select_kernel<<<NN / QQ, TPB, 0, stream>>>(x, pid, sqf, ws_cnt, ws_list,
                                               out_src, out_dst, out_y,
                                               out_ef, out_mask);
}